// Round 14
// baseline (1191.589 us; speedup 1.0000x reference)
//
#include <hip/hip_runtime.h>
#include <cmath>

#define NN 50000
#define EE 800000
#define H1C 128        // heads*hid layer1
#define OUTC 64
#define EDIM 32
#define NBLK 196       // ceil(NN/256)

__device__ __forceinline__ float bcast(float v, int d) {
    return __int_as_float(__builtin_amdgcn_readlane(__float_as_int(v), d));
}

// wave64 sum via DPP (LLVM AtomicOptimizer sequence); result broadcast from lane 63
template <int CTRL, int RM>
__device__ __forceinline__ float dpp_add(float x) {
    int y = __builtin_amdgcn_update_dpp(0, __float_as_int(x), CTRL, RM, 0xf, false);
    return x + __int_as_float(y);
}
__device__ __forceinline__ float wsum64(float x) {
    x = dpp_add<0x111, 0xf>(x);   // row_shr:1
    x = dpp_add<0x112, 0xf>(x);   // row_shr:2
    x = dpp_add<0x114, 0xf>(x);   // row_shr:4
    x = dpp_add<0x118, 0xf>(x);   // row_shr:8
    x = dpp_add<0x142, 0xa>(x);   // row_bcast:15 -> rows 1,3
    x = dpp_add<0x143, 0xc>(x);   // row_bcast:31 -> rows 2,3
    return __int_as_float(__builtin_amdgcn_readlane(__float_as_int(x), 63));
}

// ---------------- CSR build ----------------

__global__ void k_hist(const int* __restrict__ ei, int* deg) {
    int e = blockIdx.x * 256 + threadIdx.x;
    if (e < EE) atomicAdd(&deg[ei[EE + e]], 1);
}

__global__ void k_scan_block(const int* __restrict__ deg, int* offs, int* bsum) {
    __shared__ int s[256];
    int t = threadIdx.x;
    int gid = blockIdx.x * 256 + t;
    int v = (gid < NN) ? deg[gid] : 0;
    s[t] = v;
    __syncthreads();
    for (int off = 1; off < 256; off <<= 1) {
        int add = (t >= off) ? s[t - off] : 0;
        __syncthreads();
        s[t] += add;
        __syncthreads();
    }
    if (gid < NN) offs[gid] = s[t] - v;          // exclusive within block
    if (t == 255) bsum[blockIdx.x] = s[255];
}

__global__ void k_scan_top(const int* __restrict__ bsum, int* bexcl) {
    __shared__ int s[256];
    int t = threadIdx.x;
    int v = (t < NBLK) ? bsum[t] : 0;
    s[t] = v;
    __syncthreads();
    for (int off = 1; off < 256; off <<= 1) {
        int add = (t >= off) ? s[t - off] : 0;
        __syncthreads();
        s[t] += add;
        __syncthreads();
    }
    bexcl[t] = s[t] - v;
}

__global__ void k_scan_add(int* offs, const int* __restrict__ bexcl) {
    int gid = blockIdx.x * 256 + threadIdx.x;
    if (gid < NN) offs[gid] += bexcl[blockIdx.x];
    if (gid == 0) offs[NN] = EE;
}

__global__ void k_scatter(const int* __restrict__ ei, const int* __restrict__ offs,
                          int* deg, int2* esort) {
    int e = blockIdx.x * 256 + threadIdx.x;
    if (e >= EE) return;
    int dst = ei[EE + e];
    int idx = atomicSub(&deg[dst], 1) - 1;
    esort[offs[dst] + idx] = make_int2(ei[e], e);
}

// ---------------- fused pair of linears: oa = x@Wa+ba, ob = x@Wb+bb ----------------
// MODE 0: canonical [n][MO]; MODE 2: split-head [m>>6][n][64]

template <int MO, int MODE>
__global__ void k_lin_pair(const float* __restrict__ x,
                           const float* __restrict__ Wa, const float* __restrict__ ba,
                           const float* __restrict__ Wb, const float* __restrict__ bb,
                           float* __restrict__ oa, float* __restrict__ ob) {
    __shared__ float xsT[128][36];   // transposed tile, padded
    int n0 = blockIdx.x * 32;
    int nthr = 2 * MO;
    for (int idx = threadIdx.x; idx < 32 * 128; idx += nthr) {
        int n = idx >> 7, k = idx & 127;
        xsT[k][n] = (n0 + n < NN) ? x[(size_t)(n0 + n) * 128 + k] : 0.f;
    }
    __syncthreads();
    int t = threadIdx.x;
    const float* W  = (t < MO) ? Wa : Wb;
    const float* bp = (t < MO) ? ba : bb;
    float* op       = (t < MO) ? oa : ob;
    int m = (t < MO) ? t : t - MO;
    float bv = bp[m];
    float acc[32];
#pragma unroll
    for (int n = 0; n < 32; ++n) acc[n] = bv;
#pragma unroll 2
    for (int k = 0; k < 128; ++k) {
        float w = W[k * MO + m];
        const float4* row = reinterpret_cast<const float4*>(&xsT[k][0]);
#pragma unroll
        for (int c = 0; c < 8; ++c) {
            float4 v = row[c];
            acc[4 * c + 0] = fmaf(v.x, w, acc[4 * c + 0]);
            acc[4 * c + 1] = fmaf(v.y, w, acc[4 * c + 1]);
            acc[4 * c + 2] = fmaf(v.z, w, acc[4 * c + 2]);
            acc[4 * c + 3] = fmaf(v.w, w, acc[4 * c + 3]);
        }
    }
#pragma unroll
    for (int n = 0; n < 32; ++n) {
        if (n0 + n < NN) {
            if (MODE == 2)
                op[(size_t)(m >> 6) * NN * 64 + (size_t)(n0 + n) * 64 + (m & 63)] = acc[n];
            else
                op[(size_t)(n0 + n) * MO + m] = acc[n];
        }
    }
}

// ---------------- shared per-(dst,head) edge machinery (64 channels/wave) ----------------

__device__ __forceinline__ float dotw(float av, const float (&wr)[32]) {
    float t = 0.f, u = 0.f;
#pragma unroll
    for (int d = 0; d < 16; ++d) t = fmaf(bcast(av, d), wr[d], t);
#pragma unroll
    for (int d = 16; d < 32; ++d) u = fmaf(bcast(av, d), wr[d], u);
    return t + u;
}

__device__ __forceinline__ void finw(float xlv, float q, float xrv, float a,
                                     float& mr, float& s, float& acc) {
    float m = (xlv + xrv) + q;
    m = m > 0.f ? m : 0.2f * m;
    float p = wsum64(m * a);
    float nm = fmaxf(mr, p);
    float sc = __expf(mr - nm), e = __expf(p - nm);
    s = s * sc + e; acc = fmaf(acc, sc, e * xlv); mr = nm;
}

// depth-4 prefetched scan over one dst's CSR segment; 64 channels per wave
__device__ __forceinline__ void edge_scan(const int2* __restrict__ esort, int beg, int end,
                                          const float* __restrict__ xlh,
                                          const float* __restrict__ ea,
                                          const float (&wr)[32], float xrv, float a, int lane,
                                          float& mr, float& s, float& acc, float& easum) {
    float xlA = 0.f, avA = 0.f, xlB = 0.f, avB = 0.f;
    float xlC = 0.f, avC = 0.f, xlD = 0.f, avD = 0.f;
#define RELOAD(S, J)                                                     \
    if ((J) < end) {                                                     \
        int2 ed = esort[(J)];                                            \
        xl##S = xlh[(size_t)ed.x * 64 + lane];                           \
        av##S = ea[(size_t)ed.y * EDIM + (lane & 31)];                   \
    }
#define PROC(S)                                                          \
    do { easum += av##S; float q = dotw(av##S, wr);                      \
         finw(xl##S, q, xrv, a, mr, s, acc); } while (0)
    RELOAD(A, beg); RELOAD(B, beg + 1); RELOAD(C, beg + 2); RELOAD(D, beg + 3);
    int j = beg;
    for (; j + 4 <= end; j += 4) {
        PROC(A); RELOAD(A, j + 4);
        PROC(B); RELOAD(B, j + 5);
        PROC(C); RELOAD(C, j + 6);
        PROC(D); RELOAD(D, j + 7);
    }
    int rem = end - j;
    if (rem > 0) PROC(A);
    if (rem > 1) PROC(B);
    if (rem > 2) PROC(C);
#undef RELOAD
#undef PROC
}

// ---------------- fused edge phase, layer 1: one wave per (dst, head) ----------------

__global__ void __launch_bounds__(256, 8) k_l1(
    const int2* __restrict__ esort, const int* __restrict__ offs,
    const float* __restrict__ ea, const float* __restrict__ We,
    const float* __restrict__ att, const float* __restrict__ xl,  // split [head][NN][64]
    const float* __restrict__ xr,                                 // split [head][NN][64]
    const float* __restrict__ bias, float* __restrict__ hb) {
    int lane = threadIdx.x & 63;
    int w = threadIdx.x >> 6;            // 0..3
    int head = w & 1;
    int dst = blockIdx.x * 2 + (w >> 1);
    if (dst >= NN) return;
    float wr[32];
#pragma unroll
    for (int d = 0; d < 32; ++d) wr[d] = We[d * H1C + head * 64 + lane];
    const float* xlh = xl + (size_t)head * NN * 64;
    const float* xrh = xr + (size_t)head * NN * 64;
    int beg = offs[dst], end = offs[dst + 1];
    int n = end - beg;
    float a = att[head * 64 + lane];
    float xrv = xrh[(size_t)dst * 64 + lane];
    float mr = -INFINITY, s = 0.f, acc = 0.f, easum = 0.f;

    edge_scan(esort, beg, end, xlh, ea, wr, xrv, a, lane, mr, s, acc, easum);

    // self loop: attr = mean of incoming edge attrs (0 if no edges)
    float lav = easum * ((n > 0) ? (1.f / (float)n) : 1.f);
    float q = dotw(lav, wr);
    float sxl = xlh[(size_t)dst * 64 + lane];
    finw(sxl, q, xrv, a, mr, s, acc);

    float h = acc / (s + 1e-16f) + bias[head * 64 + lane];
    hb[(size_t)dst * H1C + head * 64 + lane] = h > 0.f ? h : expm1f(h);
}

// ---------------- fused edge phase, layer 2 (1 head x 64) ----------------

__global__ void __launch_bounds__(256, 8) k_l2(
    const int2* __restrict__ esort, const int* __restrict__ offs,
    const float* __restrict__ ea, const float* __restrict__ We,
    const float* __restrict__ att, const float* __restrict__ xl,
    const float* __restrict__ xr, const float* __restrict__ bias,
    float* __restrict__ out) {
    int lane = threadIdx.x & 63;
    float wr[32];
#pragma unroll
    for (int d = 0; d < 32; ++d) wr[d] = We[d * OUTC + lane];
    int dst = (blockIdx.x << 2) + (threadIdx.x >> 6);
    if (dst >= NN) return;
    int beg = offs[dst], end = offs[dst + 1];
    int n = end - beg;
    float a = att[lane];
    size_t db = (size_t)dst * OUTC;
    float xrv = xr[db + lane];
    float mr = -INFINITY, s = 0.f, acc = 0.f, easum = 0.f;

    edge_scan(esort, beg, end, xl, ea, wr, xrv, a, lane, mr, s, acc, easum);

    float lav = easum * ((n > 0) ? (1.f / (float)n) : 1.f);
    float q = dotw(lav, wr);
    float sxl = xl[db + lane];
    finw(sxl, q, xrv, a, mr, s, acc);

    out[db + lane] = acc / (s + 1e-16f) + bias[lane];
}

// ---------------- launch ----------------

extern "C" void kernel_launch(void* const* d_in, const int* in_sizes, int n_in,
                              void* d_out, int out_size, void* d_ws, size_t ws_size,
                              hipStream_t stream) {
    const float* x    = (const float*)d_in[0];
    const int*   ei   = (const int*)d_in[1];
    const float* ea   = (const float*)d_in[2];
    const float* Wl1  = (const float*)d_in[3];
    const float* bl1  = (const float*)d_in[4];
    const float* Wr1  = (const float*)d_in[5];
    const float* br1  = (const float*)d_in[6];
    const float* We1  = (const float*)d_in[7];
    const float* att1 = (const float*)d_in[8];
    const float* bias1= (const float*)d_in[9];
    const float* Wl2  = (const float*)d_in[10];
    const float* bl2  = (const float*)d_in[11];
    const float* Wr2  = (const float*)d_in[12];
    const float* br2  = (const float*)d_in[13];
    const float* We2  = (const float*)d_in[14];
    const float* att2 = (const float*)d_in[15];
    const float* bias2= (const float*)d_in[16];
    float* out = (float*)d_out;

    char* w = (char*)d_ws;
    int2* esort = (int2*)w;                 w += (size_t)EE * 8;        // 6.4 MB
    int*  offs  = (int*)w;                  w += (size_t)(NN + 4) * 4;
    int*  bsum  = (int*)w;                  w += 256 * 4;
    int*  bexcl = (int*)w;                  w += 256 * 4;
    int*  deg   = (int*)w;                  w += (size_t)NN * 4;
    float* xl1  = (float*)w;                w += (size_t)NN * H1C * 4;  // split [head][NN][64]
    float* xr1  = (float*)w;                w += (size_t)NN * H1C * 4;  // split
    float* hb   = (float*)w;                w += (size_t)NN * H1C * 4;  // canonical
    float* xl2  = (float*)w;                w += (size_t)NN * OUTC * 4;
    float* xr2  = (float*)w;                w += (size_t)NN * OUTC * 4;

    (void)hipMemsetAsync(deg, 0, (size_t)NN * 4, stream);

    // CSR build (edges sorted by dst)
    k_hist<<<(EE + 255) / 256, 256, 0, stream>>>(ei, deg);
    k_scan_block<<<NBLK, 256, 0, stream>>>(deg, offs, bsum);
    k_scan_top<<<1, 256, 0, stream>>>(bsum, bexcl);
    k_scan_add<<<NBLK, 256, 0, stream>>>(offs, bexcl);
    k_scatter<<<(EE + 255) / 256, 256, 0, stream>>>(ei, offs, deg, esort);

    // layer 1
    k_lin_pair<128, 2><<<(NN + 31) / 32, 256, 0, stream>>>(x, Wl1, bl1, Wr1, br1, xl1, xr1);
    k_l1<<<(NN + 1) / 2, 256, 0, stream>>>(esort, offs, ea, We1, att1, xl1, xr1, bias1, hb);

    // layer 2
    k_lin_pair<64, 0><<<(NN + 31) / 32, 128, 0, stream>>>(hb, Wl2, bl2, Wr2, br2, xl2, xr2);
    k_l2<<<(NN + 3) / 4, 256, 0, stream>>>(esort, offs, ea, We2, att2, xl2, xr2, bias2, out);
}

// Round 15
// 886.916 us; speedup vs baseline: 1.3435x; 1.3435x over previous
//
#include <hip/hip_runtime.h>
#include <cmath>

#define NN 50000
#define EE 800000
#define H1C 128        // heads*hid layer1
#define OUTC 64
#define EDIM 32
#define NBLK 196       // ceil(NN/256)

__device__ __forceinline__ float bcast(float v, int d) {
    return __int_as_float(__builtin_amdgcn_readlane(__float_as_int(v), d));
}

// wave64 sum via DPP (LLVM AtomicOptimizer sequence); result broadcast from lane 63
template <int CTRL, int RM>
__device__ __forceinline__ float dpp_add(float x) {
    int y = __builtin_amdgcn_update_dpp(0, __float_as_int(x), CTRL, RM, 0xf, false);
    return x + __int_as_float(y);
}
__device__ __forceinline__ float wsum64(float x) {
    x = dpp_add<0x111, 0xf>(x);   // row_shr:1
    x = dpp_add<0x112, 0xf>(x);   // row_shr:2
    x = dpp_add<0x114, 0xf>(x);   // row_shr:4
    x = dpp_add<0x118, 0xf>(x);   // row_shr:8
    x = dpp_add<0x142, 0xa>(x);   // row_bcast:15 -> rows 1,3
    x = dpp_add<0x143, 0xc>(x);   // row_bcast:31 -> rows 2,3
    return __int_as_float(__builtin_amdgcn_readlane(__float_as_int(x), 63));
}

// ---------------- CSR build ----------------

__global__ void k_hist(const int* __restrict__ ei, int* deg) {
    int e = blockIdx.x * 256 + threadIdx.x;
    if (e < EE) atomicAdd(&deg[ei[EE + e]], 1);
}

__global__ void k_scan_block(const int* __restrict__ deg, int* offs, int* bsum) {
    __shared__ int s[256];
    int t = threadIdx.x;
    int gid = blockIdx.x * 256 + t;
    int v = (gid < NN) ? deg[gid] : 0;
    s[t] = v;
    __syncthreads();
    for (int off = 1; off < 256; off <<= 1) {
        int add = (t >= off) ? s[t - off] : 0;
        __syncthreads();
        s[t] += add;
        __syncthreads();
    }
    if (gid < NN) offs[gid] = s[t] - v;          // exclusive within block
    if (t == 255) bsum[blockIdx.x] = s[255];
}

__global__ void k_scan_top(const int* __restrict__ bsum, int* bexcl) {
    __shared__ int s[256];
    int t = threadIdx.x;
    int v = (t < NBLK) ? bsum[t] : 0;
    s[t] = v;
    __syncthreads();
    for (int off = 1; off < 256; off <<= 1) {
        int add = (t >= off) ? s[t - off] : 0;
        __syncthreads();
        s[t] += add;
        __syncthreads();
    }
    bexcl[t] = s[t] - v;
}

__global__ void k_scan_add(int* offs, const int* __restrict__ bexcl) {
    int gid = blockIdx.x * 256 + threadIdx.x;
    if (gid < NN) offs[gid] += bexcl[blockIdx.x];
    if (gid == 0) offs[NN] = EE;
}

__global__ void k_scatter(const int* __restrict__ ei, const int* __restrict__ offs,
                          int* deg, int2* esort) {
    int e = blockIdx.x * 256 + threadIdx.x;
    if (e >= EE) return;
    int dst = ei[EE + e];
    int idx = atomicSub(&deg[dst], 1) - 1;
    esort[offs[dst] + idx] = make_int2(ei[e], e);
}

// ---------------- fused pair of linears: oa = x@Wa+ba, ob = x@Wb+bb ----------------
// MODE 0: canonical [n][MO]; MODE 2: split-head [m>>6][n][64]

template <int MO, int MODE>
__global__ void k_lin_pair(const float* __restrict__ x,
                           const float* __restrict__ Wa, const float* __restrict__ ba,
                           const float* __restrict__ Wb, const float* __restrict__ bb,
                           float* __restrict__ oa, float* __restrict__ ob) {
    __shared__ float xsT[128][36];   // transposed tile, padded
    int n0 = blockIdx.x * 32;
    int nthr = 2 * MO;
    for (int idx = threadIdx.x; idx < 32 * 128; idx += nthr) {
        int n = idx >> 7, k = idx & 127;
        xsT[k][n] = (n0 + n < NN) ? x[(size_t)(n0 + n) * 128 + k] : 0.f;
    }
    __syncthreads();
    int t = threadIdx.x;
    const float* W  = (t < MO) ? Wa : Wb;
    const float* bp = (t < MO) ? ba : bb;
    float* op       = (t < MO) ? oa : ob;
    int m = (t < MO) ? t : t - MO;
    float bv = bp[m];
    float acc[32];
#pragma unroll
    for (int n = 0; n < 32; ++n) acc[n] = bv;
#pragma unroll 2
    for (int k = 0; k < 128; ++k) {
        float w = W[k * MO + m];
        const float4* row = reinterpret_cast<const float4*>(&xsT[k][0]);
#pragma unroll
        for (int c = 0; c < 8; ++c) {
            float4 v = row[c];
            acc[4 * c + 0] = fmaf(v.x, w, acc[4 * c + 0]);
            acc[4 * c + 1] = fmaf(v.y, w, acc[4 * c + 1]);
            acc[4 * c + 2] = fmaf(v.z, w, acc[4 * c + 2]);
            acc[4 * c + 3] = fmaf(v.w, w, acc[4 * c + 3]);
        }
    }
#pragma unroll
    for (int n = 0; n < 32; ++n) {
        if (n0 + n < NN) {
            if (MODE == 2)
                op[(size_t)(m >> 6) * NN * 64 + (size_t)(n0 + n) * 64 + (m & 63)] = acc[n];
            else
                op[(size_t)(n0 + n) * MO + m] = acc[n];
        }
    }
}

// ---------------- shared per-(dst,head) edge machinery (64 channels/wave) ----------------

__device__ __forceinline__ float dotw(float av, const float (&wr)[32]) {
    float t = 0.f, u = 0.f;
#pragma unroll
    for (int d = 0; d < 16; ++d) t = fmaf(bcast(av, d), wr[d], t);
#pragma unroll
    for (int d = 16; d < 32; ++d) u = fmaf(bcast(av, d), wr[d], u);
    return t + u;
}

__device__ __forceinline__ void finw(float xlv, float q, float xrv, float a,
                                     float& mr, float& s, float& acc) {
    float m = (xlv + xrv) + q;
    m = m > 0.f ? m : 0.2f * m;
    float p = wsum64(m * a);
    float nm = fmaxf(mr, p);
    float sc = __expf(mr - nm), e = __expf(p - nm);
    s = s * sc + e; acc = fmaf(acc, sc, e * xlv); mr = nm;
}

// depth-4 prefetched scan over one dst's CSR segment; 64 channels per wave
__device__ __forceinline__ void edge_scan(const int2* __restrict__ esort, int beg, int end,
                                          const float* __restrict__ xlh,
                                          const float* __restrict__ ea,
                                          const float (&wr)[32], float xrv, float a, int lane,
                                          float& mr, float& s, float& acc, float& easum) {
    float xlA = 0.f, avA = 0.f, xlB = 0.f, avB = 0.f;
    float xlC = 0.f, avC = 0.f, xlD = 0.f, avD = 0.f;
#define RELOAD(S, J)                                                     \
    if ((J) < end) {                                                     \
        int2 ed = esort[(J)];                                            \
        xl##S = xlh[(size_t)ed.x * 64 + lane];                           \
        av##S = ea[(size_t)ed.y * EDIM + (lane & 31)];                   \
    }
#define PROC(S)                                                          \
    do { easum += av##S; float q = dotw(av##S, wr);                      \
         finw(xl##S, q, xrv, a, mr, s, acc); } while (0)
    RELOAD(A, beg); RELOAD(B, beg + 1); RELOAD(C, beg + 2); RELOAD(D, beg + 3);
    int j = beg;
    for (; j + 4 <= end; j += 4) {
        PROC(A); RELOAD(A, j + 4);
        PROC(B); RELOAD(B, j + 5);
        PROC(C); RELOAD(C, j + 6);
        PROC(D); RELOAD(D, j + 7);
    }
    int rem = end - j;
    if (rem > 0) PROC(A);
    if (rem > 1) PROC(B);
    if (rem > 2) PROC(C);
#undef RELOAD
#undef PROC
}

// ---------------- fused edge phase, layer 1: one wave per (dst, head) ----------------

__global__ void __launch_bounds__(256, 4) k_l1(
    const int2* __restrict__ esort, const int* __restrict__ offs,
    const float* __restrict__ ea, const float* __restrict__ We,
    const float* __restrict__ att, const float* __restrict__ xl,  // split [head][NN][64]
    const float* __restrict__ xr,                                 // split [head][NN][64]
    const float* __restrict__ bias, float* __restrict__ hb) {
    int lane = threadIdx.x & 63;
    int w = threadIdx.x >> 6;            // 0..3
    int head = w & 1;
    int dst = blockIdx.x * 2 + (w >> 1);
    if (dst >= NN) return;
    float wr[32];
#pragma unroll
    for (int d = 0; d < 32; ++d) wr[d] = We[d * H1C + head * 64 + lane];
    const float* xlh = xl + (size_t)head * NN * 64;
    const float* xrh = xr + (size_t)head * NN * 64;
    int beg = offs[dst], end = offs[dst + 1];
    int n = end - beg;
    float a = att[head * 64 + lane];
    float xrv = xrh[(size_t)dst * 64 + lane];
    float mr = -INFINITY, s = 0.f, acc = 0.f, easum = 0.f;

    edge_scan(esort, beg, end, xlh, ea, wr, xrv, a, lane, mr, s, acc, easum);

    // self loop: attr = mean of incoming edge attrs (0 if no edges)
    float lav = easum * ((n > 0) ? (1.f / (float)n) : 1.f);
    float q = dotw(lav, wr);
    float sxl = xlh[(size_t)dst * 64 + lane];
    finw(sxl, q, xrv, a, mr, s, acc);

    float h = acc / (s + 1e-16f) + bias[head * 64 + lane];
    hb[(size_t)dst * H1C + head * 64 + lane] = h > 0.f ? h : expm1f(h);
}

// ---------------- fused edge phase, layer 2 (1 head x 64) ----------------

__global__ void __launch_bounds__(256, 4) k_l2(
    const int2* __restrict__ esort, const int* __restrict__ offs,
    const float* __restrict__ ea, const float* __restrict__ We,
    const float* __restrict__ att, const float* __restrict__ xl,
    const float* __restrict__ xr, const float* __restrict__ bias,
    float* __restrict__ out) {
    int lane = threadIdx.x & 63;
    float wr[32];
#pragma unroll
    for (int d = 0; d < 32; ++d) wr[d] = We[d * OUTC + lane];
    int dst = (blockIdx.x << 2) + (threadIdx.x >> 6);
    if (dst >= NN) return;
    int beg = offs[dst], end = offs[dst + 1];
    int n = end - beg;
    float a = att[lane];
    size_t db = (size_t)dst * OUTC;
    float xrv = xr[db + lane];
    float mr = -INFINITY, s = 0.f, acc = 0.f, easum = 0.f;

    edge_scan(esort, beg, end, xl, ea, wr, xrv, a, lane, mr, s, acc, easum);

    float lav = easum * ((n > 0) ? (1.f / (float)n) : 1.f);
    float q = dotw(lav, wr);
    float sxl = xl[db + lane];
    finw(sxl, q, xrv, a, mr, s, acc);

    out[db + lane] = acc / (s + 1e-16f) + bias[lane];
}

// ---------------- launch ----------------

extern "C" void kernel_launch(void* const* d_in, const int* in_sizes, int n_in,
                              void* d_out, int out_size, void* d_ws, size_t ws_size,
                              hipStream_t stream) {
    const float* x    = (const float*)d_in[0];
    const int*   ei   = (const int*)d_in[1];
    const float* ea   = (const float*)d_in[2];
    const float* Wl1  = (const float*)d_in[3];
    const float* bl1  = (const float*)d_in[4];
    const float* Wr1  = (const float*)d_in[5];
    const float* br1  = (const float*)d_in[6];
    const float* We1  = (const float*)d_in[7];
    const float* att1 = (const float*)d_in[8];
    const float* bias1= (const float*)d_in[9];
    const float* Wl2  = (const float*)d_in[10];
    const float* bl2  = (const float*)d_in[11];
    const float* Wr2  = (const float*)d_in[12];
    const float* br2  = (const float*)d_in[13];
    const float* We2  = (const float*)d_in[14];
    const float* att2 = (const float*)d_in[15];
    const float* bias2= (const float*)d_in[16];
    float* out = (float*)d_out;

    char* w = (char*)d_ws;
    int2* esort = (int2*)w;                 w += (size_t)EE * 8;        // 6.4 MB
    int*  offs  = (int*)w;                  w += (size_t)(NN + 4) * 4;
    int*  bsum  = (int*)w;                  w += 256 * 4;
    int*  bexcl = (int*)w;                  w += 256 * 4;
    int*  deg   = (int*)w;                  w += (size_t)NN * 4;
    float* xl1  = (float*)w;                w += (size_t)NN * H1C * 4;  // split [head][NN][64]
    float* xr1  = (float*)w;                w += (size_t)NN * H1C * 4;  // split
    float* hb   = (float*)w;                w += (size_t)NN * H1C * 4;  // canonical
    float* xl2  = (float*)w;                w += (size_t)NN * OUTC * 4;
    float* xr2  = (float*)w;                w += (size_t)NN * OUTC * 4;

    (void)hipMemsetAsync(deg, 0, (size_t)NN * 4, stream);

    // CSR build (edges sorted by dst)
    k_hist<<<(EE + 255) / 256, 256, 0, stream>>>(ei, deg);
    k_scan_block<<<NBLK, 256, 0, stream>>>(deg, offs, bsum);
    k_scan_top<<<1, 256, 0, stream>>>(bsum, bexcl);
    k_scan_add<<<NBLK, 256, 0, stream>>>(offs, bexcl);
    k_scatter<<<(EE + 255) / 256, 256, 0, stream>>>(ei, offs, deg, esort);

    // layer 1
    k_lin_pair<128, 2><<<(NN + 31) / 32, 256, 0, stream>>>(x, Wl1, bl1, Wr1, br1, xl1, xr1);
    k_l1<<<(NN + 1) / 2, 256, 0, stream>>>(esort, offs, ea, We1, att1, xl1, xr1, bias1, hb);

    // layer 2
    k_lin_pair<64, 0><<<(NN + 31) / 32, 128, 0, stream>>>(hb, Wl2, bl2, Wr2, br2, xl2, xr2);
    k_l2<<<(NN + 3) / 4, 256, 0, stream>>>(esort, offs, ea, We2, att2, xl2, xr2, bias2, out);
}